// Round 1
// baseline (206.299 us; speedup 1.0000x reference)
//
#include <hip/hip_runtime.h>

#define VOCAB 8192
#define CTX 4
#define BATCH 1024
#define OBLK 16                 // fc_w rows (output columns) per workgroup
#define NCHUNK (OBLK * CTX)     // 64 chunks of VOCAB floats each

// One workgroup: 1024 threads (thread t == batch b), 16 consecutive output
// columns o0..o0+15. Streams a contiguous 2 MB slice of fc_w through a
// double-buffered LDS (2 x 32 KB); one random LDS gather per chunk per thread.
__global__ __launch_bounds__(1024) void cbow_kernel(
    const int*   __restrict__ contexts,   // [1024, 4] int32
    const float* __restrict__ fc_w,       // [8192, 32768] row-major f32
    const float* __restrict__ fc_b,       // [8192] f32
    float*       __restrict__ out)        // [1024, 8192] f32
{
    __shared__ float lds[2][VOCAB];       // 64 KB

    const int t  = threadIdx.x;           // == batch index b
    const int o0 = blockIdx.x * OBLK;
    const size_t base = (size_t)o0 * (CTX * VOCAB);  // start of this WG's slice

    // This thread's 4 context indices (16 B coalesced load).
    const int4 cv = ((const int4*)contexts)[t];
    const int cc[4] = {cv.x, cv.y, cv.z, cv.w};      // scalarized (static idx only)

    // Accumulators init with bias (uniform per WG -> scalar loads).
    float acc[OBLK];
#pragma unroll
    for (int j = 0; j < OBLK; ++j) acc[j] = fc_b[o0 + j];

    // Prologue: stage chunk 0 into lds[0]. 8192 floats / 1024 thr = 2x float4.
    {
        const float4* src = (const float4*)(fc_w + base);
        float4 a  = src[t];
        float4 b2 = src[1024 + t];
        float4* dst = (float4*)lds[0];
        dst[t]        = a;
        dst[1024 + t] = b2;
    }
    __syncthreads();

    // Main loop: chunk k lives in lds[k&1]; chunk k = row j=(k>>2), seg i=(k&3),
    // at fc_w offset base + k*VOCAB (slice is contiguous: pure sequential stream).
#pragma unroll
    for (int k = 0; k < NCHUNK; ++k) {
        float4 a, b2;
        if (k < NCHUNK - 1) {
            const float4* src = (const float4*)(fc_w + base + (size_t)(k + 1) * VOCAB);
            a  = src[t];                  // issue next-chunk loads first
            b2 = src[1024 + t];
        }

        // Gather for chunk k (1 LDS read; random bank, ~2-way avg conflict: free-ish)
        acc[k >> 2] += lds[k & 1][cc[k & 3]];

        if (k < NCHUNK - 1) {
            float4* dst = (float4*)lds[(k + 1) & 1];   // write buffer != read buffer
            dst[t]        = a;
            dst[1024 + t] = b2;
        }
        __syncthreads();   // one barrier per chunk: writes visible, reads drained
    }

    // Epilogue: thread t writes out[t, o0..o0+15] = 64 contiguous bytes
    // (one full cache line per thread, fully written -> no partial-line waste).
    float4* op = (float4*)(out + (size_t)t * VOCAB + o0);
#pragma unroll
    for (int j = 0; j < OBLK / 4; ++j) {
        float4 v;
        v.x = acc[4 * j + 0];
        v.y = acc[4 * j + 1];
        v.z = acc[4 * j + 2];
        v.w = acc[4 * j + 3];
        op[j] = v;
    }
}

extern "C" void kernel_launch(void* const* d_in, const int* in_sizes, int n_in,
                              void* d_out, int out_size, void* d_ws, size_t ws_size,
                              hipStream_t stream) {
    const int*   contexts = (const int*)d_in[0];
    const float* fc_w     = (const float*)d_in[1];
    const float* fc_b     = (const float*)d_in[2];
    float*       out      = (float*)d_out;

    dim3 grid(VOCAB / OBLK);   // 512 workgroups, 2 resident per CU
    dim3 block(1024);
    cbow_kernel<<<grid, block, 0, stream>>>(contexts, fc_w, fc_b, out);
}

// Round 2
// 201.799 us; speedup vs baseline: 1.0223x; 1.0223x over previous
//
#include <hip/hip_runtime.h>

#define VOCAB 8192
#define CTX 4
#define BATCH 1024
#define OBLK 16                 // fc_w rows (output columns) per workgroup
#define NCHUNK (OBLK * CTX)     // 64 chunks of VOCAB floats each

// One workgroup: 1024 threads (thread t == batch b), 16 consecutive output
// columns o0..o0+15. Streams a contiguous 2 MB slice of fc_w through a
// double-buffered LDS (2 x 32 KB) with register-staged depth-2 prefetch:
// iteration k issues loads for chunk k+2, ds_writes chunk k+1 (loaded one
// full iteration ago -> counted vmcnt, latency hidden), gathers chunk k.
__global__ __launch_bounds__(1024) void cbow_kernel(
    const int*   __restrict__ contexts,   // [1024, 4] int32
    const float* __restrict__ fc_w,       // [8192, 32768] row-major f32
    const float* __restrict__ fc_b,       // [8192] f32
    float*       __restrict__ out)        // [1024, 8192] f32
{
    __shared__ float lds[2][VOCAB];       // 64 KB -> 2 blocks/CU, 32 waves/CU

    const int t  = threadIdx.x;           // == batch index b
    const int o0 = blockIdx.x * OBLK;
    const size_t base = (size_t)o0 * (CTX * VOCAB);  // this WG's contiguous slice

    // This thread's 4 context indices (16 B coalesced load).
    const int4 cv = ((const int4*)contexts)[t];
    const int cc[4] = {cv.x, cv.y, cv.z, cv.w};

    // Accumulators init with bias (uniform per WG -> scalar loads).
    float acc[OBLK];
#pragma unroll
    for (int j = 0; j < OBLK; ++j) acc[j] = fc_b[o0 + j];

    // Prologue: chunk 0 -> LDS[0]; chunk 1 -> registers (held one iteration).
    {
        const float4* s0 = (const float4*)(fc_w + base);
        float4 a = s0[t];
        float4 b = s0[1024 + t];
        float4* dst = (float4*)lds[0];
        dst[t]        = a;
        dst[1024 + t] = b;
    }
    const float4* s1 = (const float4*)(fc_w + base + VOCAB);
    float4 ra = s1[t];
    float4 rb = s1[1024 + t];
    __syncthreads();

    // Main loop. Chunk k lives in lds[k&1]; chunk k covers acc row (k>>2),
    // context position (k&3). Fully unrolled so all acc/cc/LDS indices and
    // buffer parity are compile-time (no scratch, rule #20).
#pragma unroll
    for (int k = 0; k < NCHUNK; ++k) {
        float4 na, nb;
        if (k + 2 < NCHUNK) {             // issue loads for chunk k+2 FIRST
            const float4* src = (const float4*)(fc_w + base + (size_t)(k + 2) * VOCAB);
            na = src[t];
            nb = src[1024 + t];
        }

        if (k + 1 < NCHUNK) {             // write chunk k+1 (regs from prev iter;
            float4* dst = (float4*)lds[(k + 1) & 1];   // waitcnt skips the 2 new loads)
            dst[t]        = ra;
            dst[1024 + t] = rb;
        }

        // Gather for chunk k (random-bank ds_read_b32; ~2-way avg conflict: free)
        acc[k >> 2] += lds[k & 1][cc[k & 3]];

        ra = na;
        rb = nb;
        __syncthreads();   // writes of chunk k+1 visible; reads of chunk k drained
    }

    // Epilogue: thread t writes out[t, o0..o0+15] = 64 contiguous bytes.
    float4* op = (float4*)(out + (size_t)t * VOCAB + o0);
#pragma unroll
    for (int j = 0; j < OBLK / 4; ++j) {
        float4 v;
        v.x = acc[4 * j + 0];
        v.y = acc[4 * j + 1];
        v.z = acc[4 * j + 2];
        v.w = acc[4 * j + 3];
        op[j] = v;
    }
}

extern "C" void kernel_launch(void* const* d_in, const int* in_sizes, int n_in,
                              void* d_out, int out_size, void* d_ws, size_t ws_size,
                              hipStream_t stream) {
    const int*   contexts = (const int*)d_in[0];
    const float* fc_w     = (const float*)d_in[1];
    const float* fc_b     = (const float*)d_in[2];
    float*       out      = (float*)d_out;

    dim3 grid(VOCAB / OBLK);   // 512 workgroups, 2 resident per CU (no tail)
    dim3 block(1024);
    cbow_kernel<<<grid, block, 0, stream>>>(contexts, fc_w, fc_b, out);
}

// Round 3
// 201.589 us; speedup vs baseline: 1.0234x; 1.0010x over previous
//
#include <hip/hip_runtime.h>

#define VOCAB 8192
#define CTX 4
#define BATCH 1024
#define OBLK 16                 // fc_w rows (output columns) per workgroup
#define NCHUNK (OBLK * CTX)     // 64 chunks of VOCAB floats each

// One workgroup: 1024 threads (thread t == batch b), 16 consecutive output
// columns o0..o0+15. Streams a contiguous 2 MB slice of fc_w through a
// double-buffered LDS (2 x 32 KB), register-staged depth-2 prefetch.
// KEY vs R2: raw s_barrier with only lgkmcnt(0) drained — __syncthreads()
// would force s_waitcnt vmcnt(0) per chunk (m97 barrier-drain stall),
// killing the prefetch. Here the 2 newest global loads stay in flight
// across the barrier; the ds_write of chunk k+1 gets a counted vmcnt(2).
__global__ __launch_bounds__(1024) void cbow_kernel(
    const int*   __restrict__ contexts,   // [1024, 4] int32
    const float* __restrict__ fc_w,       // [8192, 32768] row-major f32
    const float* __restrict__ fc_b,       // [8192] f32
    float*       __restrict__ out)        // [1024, 8192] f32
{
    __shared__ float lds[2][VOCAB];       // 64 KB -> 2 blocks/CU, 32 waves/CU

    const int t  = threadIdx.x;           // == batch index b
    const int o0 = blockIdx.x * OBLK;
    const size_t base = (size_t)o0 * (CTX * VOCAB);  // this WG's contiguous slice

    // This thread's 4 context indices (16 B coalesced load).
    const int4 cv = ((const int4*)contexts)[t];
    const int cc[4] = {cv.x, cv.y, cv.z, cv.w};

    // Accumulators init with bias (uniform per WG -> scalar loads).
    float acc[OBLK];
#pragma unroll
    for (int j = 0; j < OBLK; ++j) acc[j] = fc_b[o0 + j];

    // Prologue: chunk 0 -> LDS[0]; chunk 1 -> registers (held one iteration).
    {
        const float4* s0 = (const float4*)(fc_w + base);
        float4 a = s0[t];
        float4 b = s0[1024 + t];
        float4* dst = (float4*)lds[0];
        dst[t]        = a;
        dst[1024 + t] = b;
    }
    const float4* s1 = (const float4*)(fc_w + base + VOCAB);
    float4 ra = s1[t];
    float4 rb = s1[1024 + t];
    // Prologue barrier: chunk-0 ds_writes drained, chunk-1 loads stay in flight.
    asm volatile("s_waitcnt lgkmcnt(0)\n\ts_barrier" ::: "memory");

    // Main loop. Chunk k lives in lds[k&1]; acc row (k>>2), context pos (k&3).
    // Fully unrolled: all acc/cc indices and buffer parity are compile-time.
#pragma unroll
    for (int k = 0; k < NCHUNK; ++k) {
        float4 na, nb;
        if (k + 2 < NCHUNK) {             // issue loads for chunk k+2 FIRST
            const float4* src = (const float4*)(fc_w + base + (size_t)(k + 2) * VOCAB);
            na = src[t];
            nb = src[1024 + t];
        }

        if (k + 1 < NCHUNK) {             // write chunk k+1 from regs loaded one
            float4* dst = (float4*)lds[(k + 1) & 1];   // iter ago -> vmcnt(2), not 0
            dst[t]        = ra;
            dst[1024 + t] = rb;
        }

        // Gather for chunk k (random-bank ds_read_b32; ~2-way avg conflict: free)
        acc[k >> 2] += lds[k & 1][cc[k & 3]];

        ra = na;
        rb = nb;

        // Cross-wave hazards are LDS-only: drain lgkmcnt, NOT vmcnt, then barrier.
        // Single volatile asm = code-motion fence (no LDS op crosses the barrier).
        if (k < NCHUNK - 1)
            asm volatile("s_waitcnt lgkmcnt(0)\n\ts_barrier" ::: "memory");
    }

    // Epilogue: thread t writes out[t, o0..o0+15] = 64 contiguous bytes
    // (one full cache line per thread, fully written).
    float4* op = (float4*)(out + (size_t)t * VOCAB + o0);
#pragma unroll
    for (int j = 0; j < OBLK / 4; ++j) {
        float4 v;
        v.x = acc[4 * j + 0];
        v.y = acc[4 * j + 1];
        v.z = acc[4 * j + 2];
        v.w = acc[4 * j + 3];
        op[j] = v;
    }
}

extern "C" void kernel_launch(void* const* d_in, const int* in_sizes, int n_in,
                              void* d_out, int out_size, void* d_ws, size_t ws_size,
                              hipStream_t stream) {
    const int*   contexts = (const int*)d_in[0];
    const float* fc_w     = (const float*)d_in[1];
    const float* fc_b     = (const float*)d_in[2];
    float*       out      = (float*)d_out;

    dim3 grid(VOCAB / OBLK);   // 512 workgroups, 2 resident per CU (no tail)
    dim3 block(1024);
    cbow_kernel<<<grid, block, 0, stream>>>(contexts, fc_w, fc_b, out);
}